// Round 1
// baseline (3782.273 us; speedup 1.0000x reference)
//
#include <hip/hip_runtime.h>
#include <math.h>

#define NPTS  32768
#define NB    2
#define NQ    (NB*NPTS)
#define KK    16
#define TILE  1024
#define EPS   1e-6f

// stats / coef element offsets
#define S_L1 0
#define S_L2 32
#define S_P1 64
#define S_P2 96
#define S_SC 160
#define C_L1 0
#define C_L2 32
#define C_P1 64
#define C_P2 96
#define C_SC 160

// workspace element offsets (4-byte units)
#define WS_X1   (NQ*16)
#define WS_T2   (NQ*32)
#define WS_T4   (NQ*48)
#define WS_STAT (NQ*80)
#define WS_COEF (NQ*80 + 512)

__device__ __forceinline__ float wred64(float v) {
#pragma unroll
  for (int m = 32; m > 0; m >>= 1) v += __shfl_xor(v, m, 64);
  return v;
}

// ---------------- zero the stats area ----------------
__global__ void k_zero(float* __restrict__ stats) {
  int i = threadIdx.x;
  if (i < 320) stats[i] = 0.f;
}

// ---------------- brute-force exact KNN ----------------
// block = 256 threads (4 waves), 128 queries/block; waves {0,1} and {2,3} are
// split-2 partners over the candidate set (each scans half of every tile).
__launch_bounds__(256)
__global__ void k_knn(const float* __restrict__ coords, int* __restrict__ oidx) {
  __shared__ float4 sp[TILE];        // 16 KB candidate tile (x,y,z,|p|^2)
  __shared__ float  smd[256*KK];     // 16 KB merge dists
  __shared__ int    smi[256*KK];     // 16 KB merge idx
  const int tid  = threadIdx.x;
  const int wave = tid >> 6, lane = tid & 63;
  const int sub  = wave & 1;
  const int qbase = blockIdx.x * 128;
  const int b = qbase >> 15;                       // blocks never straddle batches
  const int q = qbase + ((wave >> 1) << 6) + lane; // global query id
  const int n = q & (NPTS - 1);
  const float* __restrict__ cb = coords + (size_t)b * (NPTS*3);
  const float qx = cb[n*3+0], qy = cb[n*3+1], qz = cb[n*3+2];
  const float qsq = qx*qx + qy*qy + qz*qz;

  float dl[KK]; int il[KK];
#pragma unroll
  for (int i = 0; i < KK; ++i) { dl[i] = 1e30f; il[i] = 0; }

  for (int base = 0; base < NPTS; base += TILE) {
#pragma unroll
    for (int t = 0; t < TILE/256; ++t) {
      int j = base + t*256 + tid;
      float x = cb[j*3+0], y = cb[j*3+1], z = cb[j*3+2];
      sp[t*256 + tid] = make_float4(x, y, z, x*x + y*y + z*z);
    }
    __syncthreads();
    const int j0 = sub * (TILE/2);
#pragma unroll 2
    for (int j = j0; j < j0 + TILE/2; ++j) {
      float4 p = sp[j];                              // broadcast LDS read
      float d = qsq + p.w - 2.f*(qx*p.x + qy*p.y + qz*p.z); // == reference formula
      if (d < dl[KK-1]) {                            // strict < : top_k tie-break
        float cd = d; int ci = base + j;
#pragma unroll
        for (int i = 0; i < KK; ++i) {               // branch-free bubble insert
          bool sw = cd < dl[i];
          float td = dl[i]; int ti = il[i];
          dl[i] = sw ? cd : td; il[i] = sw ? ci : ti;
          cd = sw ? td : cd;   ci = sw ? ti : ci;
        }
      }
    }
    __syncthreads();
  }
#pragma unroll
  for (int i = 0; i < KK; ++i) { smd[tid*KK+i] = dl[i]; smi[tid*KK+i] = il[i]; }
  __syncthreads();
  if (sub == 0) {                                    // merge partner's half
    const int pt = tid + 64;
#pragma unroll
    for (int i = 0; i < KK; ++i) {
      float cd = smd[pt*KK+i]; int ci = smi[pt*KK+i];
      if (cd < dl[KK-1]) {
#pragma unroll
        for (int t = 0; t < KK; ++t) {
          bool sw = cd < dl[t];
          float td = dl[t]; int ti = il[t];
          dl[t] = sw ? cd : td; il[t] = sw ? ci : ti;
          cd = sw ? td : cd;   ci = sw ? ti : ci;
        }
      }
    }
#pragma unroll
    for (int i = 0; i < KK; ++i) oidx[(size_t)q*KK + i] = il[i];
  }
}

// ---------------- mlp1 (leaky 0.2) + shortcut BN stats ----------------
__global__ void k_mlp1(const float* __restrict__ features,
                       const float* __restrict__ W1, const float* __restrict__ b1,
                       const float* __restrict__ Wsc, const float* __restrict__ bsc,
                       float* __restrict__ x1, float* __restrict__ stats) {
  __shared__ float sW1[128], sb1[16], sWsc[512], sbsc[64];
  int tid = threadIdx.x;
  if (tid < 128) sW1[tid] = W1[tid];
  if (tid < 16)  sb1[tid] = b1[tid];
  if (tid < 64)  sbsc[tid] = bsc[tid];
  for (int i = tid; i < 512; i += 256) sWsc[i] = Wsc[i];
  __syncthreads();
  int q = blockIdx.x*256 + tid;
  int b = q >> 15, n = q & (NPTS-1);
  float f[8];
#pragma unroll
  for (int c = 0; c < 8; ++c) f[c] = features[((size_t)b*8 + c)*NPTS + n];
#pragma unroll
  for (int co = 0; co < 16; ++co) {
    float a = sb1[co];
#pragma unroll
    for (int c = 0; c < 8; ++c) a += f[c]*sW1[co*8+c];
    x1[(size_t)q*16 + co] = a > 0.f ? a : 0.2f*a;
  }
  int lane = tid & 63;
#pragma unroll
  for (int co = 0; co < 64; ++co) {
    float a = sbsc[co];
#pragma unroll
    for (int c = 0; c < 8; ++c) a += f[c]*sWsc[co*8+c];
    float s = wred64(a), ss = wred64(a*a);
    if (lane == 0) { atomicAdd(&stats[S_SC+co], s); atomicAdd(&stats[S_SC+64+co], ss); }
  }
}

// ---------------- BN stats for BOTH LSE geometric encodings ----------------
__global__ void k_lsestats(const float* __restrict__ coords, const int* __restrict__ idx,
                           const float* __restrict__ Wl1, const float* __restrict__ bl1,
                           const float* __restrict__ Wl2, const float* __restrict__ bl2,
                           float* __restrict__ stats) {
  __shared__ float sW1[160], sb1[16], sW2[160], sb2[16];
  __shared__ float red[4][64];
  int tid = threadIdx.x;
  for (int i = tid; i < 160; i += 256) { sW1[i] = Wl1[i]; sW2[i] = Wl2[i]; }
  if (tid < 16) { sb1[tid] = bl1[tid]; sb2[tid] = bl2[tid]; }
  __syncthreads();
  int t = blockIdx.x*256 + tid;         // (b,n,k) flat
  int q = t >> 4;
  int b = q >> 15, n = q & (NPTS-1);
  const float* cb = coords + (size_t)b*(NPTS*3);
  int j = idx[t];
  float cx = cb[n*3], cy = cb[n*3+1], cz = cb[n*3+2];
  float px = cb[j*3], py = cb[j*3+1], pz = cb[j*3+2];
  float cat[10] = {cx,cy,cz,px,py,pz,cx-px,cy-py,cz-pz,1.f};
  int wave = tid >> 6, lane = tid & 63;
#pragma unroll
  for (int co = 0; co < 16; ++co) {
    float a1 = sb1[co], a2 = sb2[co];
#pragma unroll
    for (int d0 = 0; d0 < 10; ++d0) { a1 += cat[d0]*sW1[co*10+d0]; a2 += cat[d0]*sW2[co*10+d0]; }
    float s1 = wred64(a1), q1 = wred64(a1*a1);
    float s2 = wred64(a2), q2 = wred64(a2*a2);
    if (lane == 0) { red[wave][co]=s1; red[wave][16+co]=q1; red[wave][32+co]=s2; red[wave][48+co]=q2; }
  }
  __syncthreads();
  if (tid < 64) {
    float v = red[0][tid] + red[1][tid] + red[2][tid] + red[3][tid];
    int grp = tid >> 4, c = tid & 15;
    int off = (grp == 0) ? (S_L1 + c) : (grp == 1) ? (S_L1 + 16 + c)
            : (grp == 2) ? (S_L2 + c) : (S_L2 + 16 + c);
    atomicAdd(&stats[off], v);
  }
}

// ---------------- BN finalize: coef a = g*rsqrt(v+eps), c = beta - m*a ----------------
__global__ void k_bnfin(const float* __restrict__ stats, float* __restrict__ coef,
                        const float* __restrict__ gam, const float* __restrict__ bet,
                        int soff, int coff, int nch, float invc) {
  int c = threadIdx.x;
  if (c < nch) {
    float m = stats[soff + c]*invc;
    float v = stats[soff + nch + c]*invc - m*m;
    float a = gam[c]*rsqrtf(v + EPS);
    coef[coff + c] = a;
    coef[coff + nch + c] = bet[c] - m*a;
  }
}

// ---------------- LSE1 + attentive pooling 1 (pre-BN out + stats) ----------------
__launch_bounds__(256)
__global__ void k_att1(const float* __restrict__ coords, const int* __restrict__ idx,
                       const float* __restrict__ x1ws,
                       const float* __restrict__ Wl1, const float* __restrict__ bl1,
                       const float* __restrict__ Ws1, const float* __restrict__ Wp1,
                       const float* __restrict__ bp1, const float* __restrict__ coef,
                       float* __restrict__ t2, float* __restrict__ stats) {
  __shared__ float sWl[160], sbl[16];
  __shared__ float sWs[1024];
  __shared__ float sWpT[512], sbp[16];
  __shared__ float lsum[16], lsq[16];
  int tid = threadIdx.x;
  for (int i = tid; i < 160; i += 256) { int c = i/10; sWl[i] = Wl1[i]*coef[C_L1 + c]; } // fold BN scale
  if (tid < 16) sbl[tid] = bl1[tid]*coef[C_L1+tid] + coef[C_L1+16+tid];                  // fold BN shift
  for (int i = tid; i < 1024; i += 256) sWs[i] = Ws1[i];
  for (int i = tid; i < 512; i += 256) { int co = i >> 4, cp = i & 15; sWpT[i] = Wp1[cp*32 + co]; }
  if (tid < 16) { sbp[tid] = bp1[tid]; lsum[tid] = 0.f; lsq[tid] = 0.f; }
  __syncthreads();
  int gp = blockIdx.x*16 + (tid >> 4);   // point id; lane k = neighbor slot
  int k  = tid & 15;
  int b = gp >> 15, n = gp & (NPTS-1);
  const float* cb = coords + (size_t)b*(NPTS*3);
  int j = idx[(size_t)gp*KK + k];
  float cx = cb[n*3], cy = cb[n*3+1], cz = cb[n*3+2];
  float px = cb[j*3], py = cb[j*3+1], pz = cb[j*3+2];
  float cat[10] = {cx,cy,cz,px,py,pz,cx-px,cy-py,cz-pz,1.f};
  float x[32];
#pragma unroll
  for (int co = 0; co < 16; ++co) {
    float a = sbl[co];
#pragma unroll
    for (int d0 = 0; d0 < 10; ++d0) a += cat[d0]*sWl[co*10+d0];
    x[co] = a > 0.f ? a : 0.f;           // relu(BN(lse))
  }
  {
    const float4* xp = (const float4*)(x1ws + (size_t)gp*16);
    float4 u0 = xp[0], u1 = xp[1], u2 = xp[2], u3 = xp[3];
    x[16]=u0.x; x[17]=u0.y; x[18]=u0.z; x[19]=u0.w;
    x[20]=u1.x; x[21]=u1.y; x[22]=u1.z; x[23]=u1.w;
    x[24]=u2.x; x[25]=u2.y; x[26]=u2.z; x[27]=u2.w;
    x[28]=u3.x; x[29]=u3.y; x[30]=u3.z; x[31]=u3.w;
  }
  float tacc = sbp[k];
#pragma unroll
  for (int co = 0; co < 32; ++co) {
    float s = 0.f;
#pragma unroll
    for (int ci = 0; ci < 32; ++ci) s += x[ci]*sWs[co*32+ci];
    float m = s;
#pragma unroll
    for (int msk = 8; msk > 0; msk >>= 1) m = fmaxf(m, __shfl_xor(m, msk, 16));
    float e = __expf(s - m);
    float se = e;
#pragma unroll
    for (int msk = 8; msk > 0; msk >>= 1) se += __shfl_xor(se, msk, 16);
    float w = e/se;
    float fv = w*x[co];
#pragma unroll
    for (int msk = 8; msk > 0; msk >>= 1) fv += __shfl_xor(fv, msk, 16);
    tacc += fv*sWpT[co*16+k];            // lane k owns output channel k
  }
  t2[(size_t)gp*16 + k] = tacc;
  atomicAdd(&lsum[k], tacc);
  atomicAdd(&lsq[k], tacc*tacc);
  __syncthreads();
  if (tid < 16) { atomicAdd(&stats[S_P1+tid], lsum[tid]); atomicAdd(&stats[S_P1+16+tid], lsq[tid]); }
}

// ---------------- LSE2 + attentive pooling 2 ----------------
__launch_bounds__(256)
__global__ void k_att2(const float* __restrict__ coords, const int* __restrict__ idx,
                       const float* __restrict__ t2ws,
                       const float* __restrict__ Wl2, const float* __restrict__ bl2,
                       const float* __restrict__ Ws2, const float* __restrict__ Wp2,
                       const float* __restrict__ bp2, const float* __restrict__ coef,
                       float* __restrict__ t4, float* __restrict__ stats) {
  __shared__ float sWl[160], sbl[16];
  __shared__ float sWs[1024];
  __shared__ float sWpT[1024], sbp[32];
  __shared__ float sa1[16], sc1[16];
  __shared__ float lsum[32], lsq[32];
  int tid = threadIdx.x;
  for (int i = tid; i < 160; i += 256) { int c = i/10; sWl[i] = Wl2[i]*coef[C_L2 + c]; }
  if (tid < 16) sbl[tid] = bl2[tid]*coef[C_L2+tid] + coef[C_L2+16+tid];
  for (int i = tid; i < 1024; i += 256) {
    sWs[i] = Ws2[i];
    int co = i >> 5, cp = i & 31; sWpT[i] = Wp2[cp*32 + co];
  }
  if (tid < 32) { sbp[tid] = bp2[tid]; lsum[tid]=0.f; lsq[tid]=0.f; }
  if (tid < 16) { sa1[tid] = coef[C_P1+tid]; sc1[tid] = coef[C_P1+16+tid]; }
  __syncthreads();
  int gp = blockIdx.x*16 + (tid >> 4);
  int k  = tid & 15;
  int b = gp >> 15, n = gp & (NPTS-1);
  const float* cb = coords + (size_t)b*(NPTS*3);
  int j = idx[(size_t)gp*KK + k];
  float cx = cb[n*3], cy = cb[n*3+1], cz = cb[n*3+2];
  float px = cb[j*3], py = cb[j*3+1], pz = cb[j*3+2];
  float cat[10] = {cx,cy,cz,px,py,pz,cx-px,cy-py,cz-pz,1.f};
  float x[32];
#pragma unroll
  for (int co = 0; co < 16; ++co) {
    float a = sbl[co];
#pragma unroll
    for (int d0 = 0; d0 < 10; ++d0) a += cat[d0]*sWl[co*10+d0];
    x[co] = a > 0.f ? a : 0.f;
  }
  {
    const float4* xp = (const float4*)(t2ws + (size_t)gp*16);
    float4 u0 = xp[0], u1 = xp[1], u2 = xp[2], u3 = xp[3];
    float xv[16] = {u0.x,u0.y,u0.z,u0.w, u1.x,u1.y,u1.z,u1.w,
                    u2.x,u2.y,u2.z,u2.w, u3.x,u3.y,u3.z,u3.w};
#pragma unroll
    for (int c = 0; c < 16; ++c) {
      float v = xv[c]*sa1[c] + sc1[c];   // relu(BN(attpool1))
      x[16+c] = v > 0.f ? v : 0.f;
    }
  }
  float tacc0 = sbp[k], tacc1 = sbp[k+16];
#pragma unroll
  for (int co = 0; co < 32; ++co) {
    float s = 0.f;
#pragma unroll
    for (int ci = 0; ci < 32; ++ci) s += x[ci]*sWs[co*32+ci];
    float m = s;
#pragma unroll
    for (int msk = 8; msk > 0; msk >>= 1) m = fmaxf(m, __shfl_xor(m, msk, 16));
    float e = __expf(s - m);
    float se = e;
#pragma unroll
    for (int msk = 8; msk > 0; msk >>= 1) se += __shfl_xor(se, msk, 16);
    float w = e/se;
    float fv = w*x[co];
#pragma unroll
    for (int msk = 8; msk > 0; msk >>= 1) fv += __shfl_xor(fv, msk, 16);
    tacc0 += fv*sWpT[co*32+k];
    tacc1 += fv*sWpT[co*32+k+16];
  }
  t4[(size_t)gp*32 + k]      = tacc0;
  t4[(size_t)gp*32 + k + 16] = tacc1;
  atomicAdd(&lsum[k], tacc0);      atomicAdd(&lsq[k], tacc0*tacc0);
  atomicAdd(&lsum[k+16], tacc1);   atomicAdd(&lsq[k+16], tacc1*tacc1);
  __syncthreads();
  if (tid < 32) { atomicAdd(&stats[S_P2+tid], lsum[tid]); atomicAdd(&stats[S_P2+32+tid], lsq[tid]); }
}

// ---------------- final: mlp2 + BN'd shortcut + leaky 0.01, transposed store ----------------
__global__ void k_final(const float* __restrict__ t4ws, const float* __restrict__ features,
                        const float* __restrict__ W2, const float* __restrict__ b2,
                        const float* __restrict__ Wsc, const float* __restrict__ bsc,
                        const float* __restrict__ coef, float* __restrict__ out) {
  __shared__ float sW2[2048], sb2[64], sWscF[512], sbscF[64], sa[32], scc[32];
  int tid = threadIdx.x;
  for (int i = tid; i < 2048; i += 256) sW2[i] = W2[i];
  if (tid < 64) sb2[tid] = b2[tid];
  for (int i = tid; i < 512; i += 256) { int c2 = i >> 3; sWscF[i] = Wsc[i]*coef[C_SC + c2]; }
  if (tid < 64) sbscF[tid] = bsc[tid]*coef[C_SC+tid] + coef[C_SC+64+tid];
  if (tid < 32) { sa[tid] = coef[C_P2+tid]; scc[tid] = coef[C_P2+32+tid]; }
  __syncthreads();
  int q = blockIdx.x*256 + tid;
  int b = q >> 15, n = q & (NPTS-1);
  float x3[32];
  const float4* tp = (const float4*)(t4ws + (size_t)q*32);
#pragma unroll
  for (int i = 0; i < 8; ++i) {
    float4 u = tp[i];
    float v0 = u.x*sa[4*i+0] + scc[4*i+0];
    float v1 = u.y*sa[4*i+1] + scc[4*i+1];
    float v2 = u.z*sa[4*i+2] + scc[4*i+2];
    float v3 = u.w*sa[4*i+3] + scc[4*i+3];
    x3[4*i+0] = v0 > 0.f ? v0 : 0.f;
    x3[4*i+1] = v1 > 0.f ? v1 : 0.f;
    x3[4*i+2] = v2 > 0.f ? v2 : 0.f;
    x3[4*i+3] = v3 > 0.f ? v3 : 0.f;
  }
  float f[8];
#pragma unroll
  for (int c = 0; c < 8; ++c) f[c] = features[((size_t)b*8+c)*NPTS + n];
  for (int c2 = 0; c2 < 64; ++c2) {
    float acc = sb2[c2];
#pragma unroll
    for (int co = 0; co < 32; ++co) acc += x3[co]*sW2[c2*32+co];
    float sv = sbscF[c2];
#pragma unroll
    for (int c = 0; c < 8; ++c) sv += f[c]*sWscF[c2*8+c];
    float o = acc + sv;
    out[((size_t)b*64 + c2)*NPTS + n] = o > 0.f ? o : 0.01f*o;
  }
}

extern "C" void kernel_launch(void* const* d_in, const int* in_sizes, int n_in,
                              void* d_out, int out_size, void* d_ws, size_t ws_size,
                              hipStream_t stream) {
  const float* coords   = (const float*)d_in[0];
  const float* features = (const float*)d_in[1];
  const float* W1  = (const float*)d_in[2];
  const float* b1  = (const float*)d_in[3];
  const float* Wl1 = (const float*)d_in[4];
  const float* bl1 = (const float*)d_in[5];
  const float* gl1 = (const float*)d_in[6];
  const float* bl1b= (const float*)d_in[7];
  const float* Ws1 = (const float*)d_in[8];
  const float* Wp1 = (const float*)d_in[9];
  const float* bp1 = (const float*)d_in[10];
  const float* gp1 = (const float*)d_in[11];
  const float* bp1b= (const float*)d_in[12];
  const float* Wl2 = (const float*)d_in[13];
  const float* bl2 = (const float*)d_in[14];
  const float* gl2 = (const float*)d_in[15];
  const float* bl2b= (const float*)d_in[16];
  const float* Ws2 = (const float*)d_in[17];
  const float* Wp2 = (const float*)d_in[18];
  const float* bp2 = (const float*)d_in[19];
  const float* gp2 = (const float*)d_in[20];
  const float* bp2b= (const float*)d_in[21];
  const float* W2  = (const float*)d_in[22];
  const float* b2  = (const float*)d_in[23];
  const float* Wsc = (const float*)d_in[24];
  const float* bsc = (const float*)d_in[25];
  const float* gsc = (const float*)d_in[26];
  const float* bscb= (const float*)d_in[27];

  int*   idxp = (int*)d_ws;
  float* wsF  = (float*)d_ws;
  float* x1p  = wsF + WS_X1;
  float* t2p  = wsF + WS_T2;
  float* t4p  = wsF + WS_T4;
  float* stat = wsF + WS_STAT;
  float* coef = wsF + WS_COEF;
  float* outp = (float*)d_out;

  hipLaunchKernelGGL(k_zero, dim3(1), dim3(320), 0, stream, stat);
  hipLaunchKernelGGL(k_knn,  dim3(NQ/128), dim3(256), 0, stream, coords, idxp);
  hipLaunchKernelGGL(k_mlp1, dim3(NQ/256), dim3(256), 0, stream,
                     features, W1, b1, Wsc, bsc, x1p, stat);
  hipLaunchKernelGGL(k_lsestats, dim3((NQ*KK)/256), dim3(256), 0, stream,
                     coords, idxp, Wl1, bl1, Wl2, bl2, stat);
  hipLaunchKernelGGL(k_bnfin, dim3(1), dim3(64), 0, stream, stat, coef, gl1, bl1b,
                     S_L1, C_L1, 16, 1.f/(float)((size_t)NQ*KK));
  hipLaunchKernelGGL(k_bnfin, dim3(1), dim3(64), 0, stream, stat, coef, gl2, bl2b,
                     S_L2, C_L2, 16, 1.f/(float)((size_t)NQ*KK));
  hipLaunchKernelGGL(k_bnfin, dim3(1), dim3(64), 0, stream, stat, coef, gsc, bscb,
                     S_SC, C_SC, 64, 1.f/(float)NQ);
  hipLaunchKernelGGL(k_att1, dim3(NQ/16), dim3(256), 0, stream,
                     coords, idxp, x1p, Wl1, bl1, Ws1, Wp1, bp1, coef, t2p, stat);
  hipLaunchKernelGGL(k_bnfin, dim3(1), dim3(64), 0, stream, stat, coef, gp1, bp1b,
                     S_P1, C_P1, 16, 1.f/(float)NQ);
  hipLaunchKernelGGL(k_att2, dim3(NQ/16), dim3(256), 0, stream,
                     coords, idxp, t2p, Wl2, bl2, Ws2, Wp2, bp2, coef, t4p, stat);
  hipLaunchKernelGGL(k_bnfin, dim3(1), dim3(64), 0, stream, stat, coef, gp2, bp2b,
                     S_P2, C_P2, 32, 1.f/(float)NQ);
  hipLaunchKernelGGL(k_final, dim3(NQ/256), dim3(256), 0, stream,
                     t4p, features, W2, b2, Wsc, bsc, coef, outp);
}